// Round 15
// baseline (349.561 us; speedup 1.0000x reference)
//
#include <hip/hip_runtime.h>
#include <math.h>

#define NC    10
#define BATCH 256
#define IC    1152
#define LDIM  8
#define OC    16

#define NCH   96
#define CH    (IC/NCH)        // 12 i's per block (3 per wave)
#define NBLK  (NC*NCH)        // 960 blocks
#define NTHR  256
#define NTOT  (NC*BATCH*OC)   // 40960
#define NRED  160             // kR blocks / n2 partials
#define KPG   (NCH/4)         // 24 chunks per wave-group in kR
#define VPAD  17              // padded row (floats) -> 2-way LDS banks only

typedef float f32x2 __attribute__((ext_vector_type(2)));

// R8 n-major swizzle (best measured config)
__device__ __forceinline__ int xcd_swizzle(int bid, int nwg) {
    int cpx = nwg >> 3;
    return (bid & 7) * cpx + (bid >> 3);
}

// ---------------------------------------------------------------------------
// K0: transpose x[b][i][l] -> xT[i][b][l]
// ---------------------------------------------------------------------------
__global__ __launch_bounds__(256) void k0_xT(const float* __restrict__ x,
                                             float* __restrict__ xT)
{
    int u = blockIdx.x * 256 + threadIdx.x;       // < 589824
    int i = u >> 9, r = u & 511, b = r >> 1, h = r & 1;
    reinterpret_cast<float4*>(xT)[u] =
        reinterpret_cast<const float4*>(x)[((size_t)b * IC + i) * 2 + h];
}

// ---------------------------------------------------------------------------
// KA: iter-0 s partials (c uniform = 1/256). thread = b. (R14 version)
// ---------------------------------------------------------------------------
__global__ __launch_bounds__(256) void kA(
    const float* __restrict__ xT, const float* __restrict__ w,
    float* __restrict__ s_part)
{
    int wg = xcd_swizzle(blockIdx.x, NBLK);
    int n  = wg / NCH, ch = wg % NCH;
    int i0 = ch * CH;
    int t  = threadIdx.x;            // = b

    f32x2 sp2[8];
#pragma unroll
    for (int j = 0; j < 8; ++j) sp2[j] = (f32x2){0.f, 0.f};

    for (int ii = 0; ii < CH; ++ii) {
        int i = i0 + ii;
        const float4* xp = reinterpret_cast<const float4*>(xT)
                         + ((size_t)i * BATCH + t) * 2;
        float4 xa = xp[0], xb = xp[1];
        float xr[8] = {xa.x, xa.y, xa.z, xa.w, xb.x, xb.y, xb.z, xb.w};
        const f32x2* wp2 = reinterpret_cast<const f32x2*>(
            w + (size_t)__builtin_amdgcn_readfirstlane((n * IC + i) * (LDIM * OC)));
#pragma unroll
        for (int l = 0; l < LDIM; ++l) {
            f32x2 xl = {xr[l], xr[l]};
#pragma unroll
            for (int j = 0; j < 8; ++j)
                sp2[j] += wp2[l * 8 + j] * xl;    // v_pk_fma_f32
        }
    }
    float4* dst = reinterpret_cast<float4*>(s_part)
                + (((size_t)ch * NC + n) * BATCH + t) * 4;
    const float inv = 1.0f / 256.0f;
    dst[0] = make_float4(sp2[0].x*inv, sp2[0].y*inv, sp2[1].x*inv, sp2[1].y*inv);
    dst[1] = make_float4(sp2[2].x*inv, sp2[2].y*inv, sp2[3].x*inv, sp2[3].y*inv);
    dst[2] = make_float4(sp2[4].x*inv, sp2[4].y*inv, sp2[5].x*inv, sp2[5].y*inv);
    dst[3] = make_float4(sp2[6].x*inv, sp2[6].y*inv, sp2[7].x*inv, sp2[7].y*inv);
}

// ---------------------------------------------------------------------------
// KR: 160 blocks. Wave g sums chunks [g*24, g*24+24) as float4 with FOUR
// independent accumulators (fixed tree -> deterministic, ILP-4); LDS combine.
// ---------------------------------------------------------------------------
__global__ __launch_bounds__(256) void kR(const float* __restrict__ s_part,
                                          float* __restrict__ s,
                                          float* __restrict__ n2_part)
{
    __shared__ float4 lds[4][64];
    int t = threadIdx.x, lane = t & 63, g = t >> 6;
    int idx0 = blockIdx.x * 256;
    const float* base = s_part + idx0 + lane * 4;
    float4 a0 = make_float4(0,0,0,0), a1 = a0, a2 = a0, a3 = a0;
    for (int k = 0; k < KPG; k += 4) {
        float4 v0 = *reinterpret_cast<const float4*>(base + (size_t)(g*KPG + k    ) * NTOT);
        float4 v1 = *reinterpret_cast<const float4*>(base + (size_t)(g*KPG + k + 1) * NTOT);
        float4 v2 = *reinterpret_cast<const float4*>(base + (size_t)(g*KPG + k + 2) * NTOT);
        float4 v3 = *reinterpret_cast<const float4*>(base + (size_t)(g*KPG + k + 3) * NTOT);
        a0.x += v0.x; a0.y += v0.y; a0.z += v0.z; a0.w += v0.w;
        a1.x += v1.x; a1.y += v1.y; a1.z += v1.z; a1.w += v1.w;
        a2.x += v2.x; a2.y += v2.y; a2.z += v2.z; a2.w += v2.w;
        a3.x += v3.x; a3.y += v3.y; a3.z += v3.z; a3.w += v3.w;
    }
    float4 a = make_float4((a0.x+a1.x)+(a2.x+a3.x), (a0.y+a1.y)+(a2.y+a3.y),
                           (a0.z+a1.z)+(a2.z+a3.z), (a0.w+a1.w)+(a2.w+a3.w));
    lds[g][lane] = a;
    __syncthreads();
    if (t < 64) {
        float4 s0 = lds[0][t], s1 = lds[1][t], s2 = lds[2][t], s3 = lds[3][t];
        float4 sv = make_float4((s0.x+s1.x)+(s2.x+s3.x), (s0.y+s1.y)+(s2.y+s3.y),
                                (s0.z+s1.z)+(s2.z+s3.z), (s0.w+s1.w)+(s2.w+s3.w));
        *reinterpret_cast<float4*>(s + idx0 + t * 4) = sv;
        float q = sv.x*sv.x + sv.y*sv.y + sv.z*sv.z + sv.w*sv.w;
#pragma unroll
        for (int m = 32; m >= 1; m >>= 1) q += __shfl_xor(q, m, 64);
        if (t == 0) n2_part[blockIdx.x] = q;
    }
}

// ---------------------------------------------------------------------------
// KB: wave-autonomous fused routing step, betaT-free.
// Lane l owns b in {l, 64+l, 128+l, 192+l} -> softmax denominator is purely
// intra-wave (4 adds + 6 shfl). ZERO barriers in the main loop; each wave
// independently processes 3 i's. v_eff in LDS [256][17] (2-way banks = free).
// Phase 2 recomputes p j-streamed (keeps VGPR ~130). Per-wave sp partials
// combined via one-shot LDS atomicAdd + one end barrier.
//   MODE 1: v_eff = s1*sc1           (iter 2)
//   MODE 2: v_eff = s1*sc1 + s2*sc2  (iter 3)
// ---------------------------------------------------------------------------
template<int MODE>
__global__ __launch_bounds__(256, 3) void kB(
    const float* __restrict__ xT, const float* __restrict__ w,
    const float* __restrict__ s1, const float* __restrict__ n2p1,
    const float* __restrict__ s2, const float* __restrict__ n2p2,
    float* __restrict__ s_part)
{
    __shared__ float v_lds[BATCH * VPAD];    // 17.4 KB
    __shared__ float sp_lds[BATCH * VPAD];   // 17.4 KB
    __shared__ float redW[8];
    int t = threadIdx.x, lane = t & 63, wid = t >> 6;
    int wg = xcd_swizzle(blockIdx.x, NBLK);
    int n  = wg / NCH, ch = wg % NCH;
    int i0 = ch * CH;

    // squash scale(s) from n2 partials (redundant per block, fixed order)
    float q1 = (t < NRED) ? n2p1[t] : 0.f;
    float q2 = (MODE == 2 && t < NRED) ? n2p2[t] : 0.f;
#pragma unroll
    for (int m = 32; m >= 1; m >>= 1) {
        q1 += __shfl_xor(q1, m, 64);
        if (MODE == 2) q2 += __shfl_xor(q2, m, 64);
    }
    if (lane == 0) { redW[wid] = q1; redW[4 + wid] = q2; }
    __syncthreads();
    float n2a = (redW[0] + redW[1]) + (redW[2] + redW[3]);
    float sc1 = sqrtf(n2a) / (1.0f + n2a);

    // v_eff -> LDS (thread t = b), sp_lds -> 0
    {
        const f32x2* s1p = reinterpret_cast<const f32x2*>(s1)
                         + ((size_t)n * BATCH + t) * 8;
        f32x2 sv = {sc1, sc1};
        float ve[16];
#pragma unroll
        for (int j = 0; j < 8; ++j) {
            f32x2 a = s1p[j] * sv;
            ve[2*j] = a.x; ve[2*j+1] = a.y;
        }
        if (MODE == 2) {
            float n2b = (redW[4] + redW[5]) + (redW[6] + redW[7]);
            float sc2 = sqrtf(n2b) / (1.0f + n2b);
            const f32x2* s2p = reinterpret_cast<const f32x2*>(s2)
                             + ((size_t)n * BATCH + t) * 8;
            f32x2 sw = {sc2, sc2};
#pragma unroll
            for (int j = 0; j < 8; ++j) {
                f32x2 a = s2p[j] * sw;
                ve[2*j] += a.x; ve[2*j+1] += a.y;
            }
        }
#pragma unroll
        for (int e = 0; e < 16; ++e) v_lds[t * VPAD + e] = ve[e];
#pragma unroll
        for (int r = 0; r < VPAD; ++r) sp_lds[t * VPAD + r] = 0.f;
    }
    __syncthreads();

    int vb[4];
#pragma unroll
    for (int k = 0; k < 4; ++k) vb[k] = (64 * k + lane) * VPAD;

    f32x2 sp[4][8];
#pragma unroll
    for (int k = 0; k < 4; ++k)
#pragma unroll
        for (int j = 0; j < 8; ++j) sp[k][j] = (f32x2){0.f, 0.f};

    // ---- main loop: 3 i's per wave, NO barriers ----
    for (int j3 = 0; j3 < 3; ++j3) {
        int i = i0 + wid * 3 + j3;
        float xq[4][8];
#pragma unroll
        for (int k = 0; k < 4; ++k) {
            const float4* xp = reinterpret_cast<const float4*>(xT)
                             + ((size_t)i * BATCH + 64 * k + lane) * 2;
            float4 xa = xp[0], xb = xp[1];
            xq[k][0]=xa.x; xq[k][1]=xa.y; xq[k][2]=xa.z; xq[k][3]=xa.w;
            xq[k][4]=xb.x; xq[k][5]=xb.y; xq[k][6]=xb.z; xq[k][7]=xb.w;
        }
        const f32x2* wp2 = reinterpret_cast<const f32x2*>(
            w + (size_t)__builtin_amdgcn_readfirstlane((n * IC + i) * (LDIM * OC)));

        // phase 1: dots + exp (j-streamed p, v from LDS)
        float e4[4];
#pragma unroll
        for (int k = 0; k < 4; ++k) {
            float dot = 0.f;
#pragma unroll
            for (int jj = 0; jj < 8; ++jj) {
                f32x2 pj = {0.f, 0.f};
#pragma unroll
                for (int l = 0; l < LDIM; ++l) {
                    f32x2 xl = {xq[k][l], xq[k][l]};
                    pj += wp2[l * 8 + jj] * xl;
                }
                dot += pj.x * v_lds[vb[k] + 2*jj] + pj.y * v_lds[vb[k] + 2*jj + 1];
            }
            e4[k] = __expf(dot);
        }

        // intra-wave softmax denominator over all 256 b
        float esum = (e4[0] + e4[1]) + (e4[2] + e4[3]);
#pragma unroll
        for (int m = 1; m < 64; m <<= 1) esum += __shfl_xor(esum, m, 64);
        float rden = 1.0f / esum;

        // phase 2: recompute p (j-streamed), accumulate c*p
#pragma unroll
        for (int k = 0; k < 4; ++k) {
            float cs = e4[k] * rden;
            f32x2 ck = {cs, cs};
#pragma unroll
            for (int jj = 0; jj < 8; ++jj) {
                f32x2 pj = {0.f, 0.f};
#pragma unroll
                for (int l = 0; l < LDIM; ++l) {
                    f32x2 xl = {xq[k][l], xq[k][l]};
                    pj += wp2[l * 8 + jj] * xl;
                }
                sp[k][jj] += ck * pj;
            }
        }
    }

    // ---- combine 4 waves' partials (2-way-bank LDS atomics), then write ----
#pragma unroll
    for (int k = 0; k < 4; ++k)
#pragma unroll
        for (int jj = 0; jj < 8; ++jj) {
            atomicAdd(&sp_lds[vb[k] + 2*jj],     sp[k][jj].x);
            atomicAdd(&sp_lds[vb[k] + 2*jj + 1], sp[k][jj].y);
        }
    __syncthreads();

    float4* dst = reinterpret_cast<float4*>(s_part)
                + (((size_t)ch * NC + n) * BATCH + t) * 4;
#pragma unroll
    for (int qd = 0; qd < 4; ++qd) {
        dst[qd] = make_float4(sp_lds[t*VPAD + 4*qd], sp_lds[t*VPAD + 4*qd + 1],
                              sp_lds[t*VPAD + 4*qd + 2], sp_lds[t*VPAD + 4*qd + 3]);
    }
}

// ---------------------------------------------------------------------------
// K_OUT: n2 from partials; out = s * scale
// ---------------------------------------------------------------------------
__global__ __launch_bounds__(256) void k_out(const float* __restrict__ s,
                                             const float* __restrict__ n2_part,
                                             float* __restrict__ out)
{
    __shared__ float redW[4];
    int t = threadIdx.x, lane = t & 63, wid = t >> 6;
    float q = (t < NRED) ? n2_part[t] : 0.f;
#pragma unroll
    for (int m = 32; m >= 1; m >>= 1) q += __shfl_xor(q, m, 64);
    if (lane == 0) redW[wid] = q;
    __syncthreads();
    float n2 = (redW[0] + redW[1]) + (redW[2] + redW[3]);
    float sc = sqrtf(n2) / (1.0f + n2);
    int idx = blockIdx.x * 256 + t;
    out[idx] = s[idx] * sc;
}

// ---------------------------------------------------------------------------
extern "C" void kernel_launch(void* const* d_in, const int* in_sizes, int n_in,
                              void* d_out, int out_size, void* d_ws, size_t ws_size,
                              hipStream_t stream)
{
    const float* x = (const float*)d_in[0];   // [256,1152,8]
    const float* w = (const float*)d_in[1];   // [10,1152,8,16]
    float* out = (float*)d_out;               // 40960 floats
    float* ws  = (float*)d_ws;

    float* xT      = ws;                                  // 2,359,296
    float* s_part  = xT + (size_t)IC * BATCH * LDIM;      // 3,932,160
    float* s1      = s_part + (size_t)NCH * NTOT;         //    40,960
    float* s2      = s1 + NTOT;                           //    40,960
    float* s3      = s2 + NTOT;                           //    40,960
    float* n2p1    = s3 + NTOT;                           //       160
    float* n2p2    = n2p1 + NRED;                         //       160
    float* n2p3    = n2p2 + NRED;                         //       160
    // total ~26 MB of workspace

    dim3 blk(256);

    k0_xT<<<2304, blk, 0, stream>>>(x, xT);
    // iter 1: c uniform
    kA<<<NBLK, blk, 0, stream>>>(xT, w, s_part);
    kR<<<NRED, blk, 0, stream>>>(s_part, s1, n2p1);
    // iter 2: beta1 = p.v1
    kB<1><<<NBLK, blk, 0, stream>>>(xT, w, s1, n2p1, s1, n2p1, s_part);
    kR<<<NRED, blk, 0, stream>>>(s_part, s2, n2p2);
    // iter 3: beta2 = p.(v1+v2) (linearity, no beta carrier)
    kB<2><<<NBLK, blk, 0, stream>>>(xT, w, s1, n2p1, s2, n2p2, s_part);
    kR<<<NRED, blk, 0, stream>>>(s_part, s3, n2p3);
    // final squash -> out
    k_out<<<NRED, blk, 0, stream>>>(s3, n2p3, out);
}